// Round 2
// baseline (306.875 us; speedup 1.0000x reference)
//
#include <hip/hip_runtime.h>

// RefLocal: 5x5 windowed dot-product attention, fp32.
// B=8 H=96 W=96 C=192 V=96.
// R2 design: 256-thread block (4 waves) per 8x8 pixel tile; channel dim split
// across waves (4.5 waves/SIMD vs 1.1 in R1, which was latency-bound at
// Occupancy=11%, VALUBusy=15%).
//   Phase 1: C in 6 chunks of 32; halo (12x12) staged in LDS, wave g dots its
//            8-channel slice -> partial logits; LDS reduction across waves.
//   Phase 2: V in 3 chunks of 32; wave g owns 8 channels per chunk.
// LDS pixel stride 36 floats: b128 accesses spread uniformly over banks.

#define BATCH 8
#define HH 96
#define WW 96
#define CH 192
#define VV 96
#define KS 5
#define PAD 2
#define TH 8
#define TW 8
#define HT (TH + 2 * PAD) // 12
#define WT (TW + 2 * PAD) // 12
#define NPIX (HT * WT)    // 144
#define CHUNK 32          // channels staged per iteration
#define SPX 36            // LDS floats per pixel (32 data + 4 pad)
#define RSTR 101          // reduction buffer stride (odd -> conflict-free)

__global__ __launch_bounds__(256, 4) void reflocal_kernel(
    const float* __restrict__ qry, const float* __restrict__ key,
    const float* __restrict__ val, float* __restrict__ out) {
  // XCD swizzle: blockIdx round-robins across 8 XCDs; give each XCD one image.
  int braw = blockIdx.x;
  int L = (braw & 7) * 144 + (braw >> 3); // gridDim.x == 1152
  int bb = L / 144;
  int t2 = L - bb * 144;
  int tyy = t2 / 12;
  int txx = t2 - tyy * 12;
  int h0 = tyy * TH, w0 = txx * TW;

  int tid = threadIdx.x;
  int g = tid >> 6;        // wave id 0..3 (channel-slice owner)
  int p = tid & 63;        // pixel within 8x8 tile
  int ty = p >> 3, tx = p & 7;
  int h = h0 + ty, w = w0 + tx;

  // union: halo chunk (144*36=5184 floats) / logit partials (64*101=6464)
  __shared__ float s[64 * RSTR]; // 25856 B

  float lg[25];
#pragma unroll
  for (int o = 0; o < 25; ++o) lg[o] = 0.f;

  const float* qbase = qry + (size_t)((bb * HH + h) * WW + w) * CH;

  // ---- Phase 1: partial logits, C in chunks of 32 (wave slice = 8 ch) ----
  for (int c0 = 0; c0 < CH; c0 += CHUNK) {
    __syncthreads();
    for (int t = tid; t < NPIX * (CHUNK / 4); t += 256) {
      int px = t >> 3, q = t & 7;
      int ry = px / WT, rx = px - ry * WT;
      int hh = h0 - PAD + ry, ww = w0 - PAD + rx;
      float4 v4 = make_float4(0.f, 0.f, 0.f, 0.f);
      if ((unsigned)hh < HH && (unsigned)ww < WW) {
        v4 = *(const float4*)(key + (size_t)((bb * HH + hh) * WW + ww) * CH +
                              c0 + q * 4);
      }
      *(float4*)(&s[px * SPX + q * 4]) = v4;
    }
    __syncthreads();

    float4 m0 = *(const float4*)(qbase + c0 + g * 8);
    float4 m1 = *(const float4*)(qbase + c0 + g * 8 + 4);
#pragma unroll
    for (int i = 0; i < KS; ++i) {
#pragma unroll
      for (int j = 0; j < KS; ++j) {
        const float* sp = &s[((ty + i) * WT + tx + j) * SPX + g * 8];
        float4 k0 = *(const float4*)(sp);
        float4 k1 = *(const float4*)(sp + 4);
        lg[i * 5 + j] += m0.x * k0.x + m0.y * k0.y + m0.z * k0.z +
                         m0.w * k0.w + m1.x * k1.x + m1.y * k1.y +
                         m1.z * k1.z + m1.w * k1.w;
      }
    }
  }

  // ---- cross-wave logit reduction through LDS ----
  __syncthreads();
#pragma unroll
  for (int o = 0; o < 25; ++o) s[p * RSTR + g * 25 + o] = lg[o];
  __syncthreads();
#pragma unroll
  for (int o = 0; o < 25; ++o) {
    float v = s[p * RSTR + o];
#pragma unroll
    for (int g2 = 1; g2 < 4; ++g2) v += s[p * RSTR + g2 * 25 + o];
    lg[o] = v;
  }

  // ---- softmax over 25 (zero halo contributed logit 0, matching TF SAME) ----
  float mx = lg[0];
#pragma unroll
  for (int o = 1; o < 25; ++o) mx = fmaxf(mx, lg[o]);
  float sum = 0.f;
#pragma unroll
  for (int o = 0; o < 25; ++o) {
    lg[o] = __expf(lg[o] - mx);
    sum += lg[o];
  }
  float inv = 1.f / sum;
#pragma unroll
  for (int o = 0; o < 25; ++o) lg[o] *= inv;

  // ---- Phase 2: values, V in chunks of 32 (wave slice = 8 ch) ----
  float* obase = out + (size_t)((bb * HH + h) * WW + w) * VV;
  for (int v0 = 0; v0 < VV; v0 += CHUNK) {
    __syncthreads();
    for (int t = tid; t < NPIX * (CHUNK / 4); t += 256) {
      int px = t >> 3, q = t & 7;
      int ry = px / WT, rx = px - ry * WT;
      int hh = h0 - PAD + ry, ww = w0 - PAD + rx;
      float4 v4 = make_float4(0.f, 0.f, 0.f, 0.f);
      if ((unsigned)hh < HH && (unsigned)ww < WW) {
        v4 = *(const float4*)(val + (size_t)((bb * HH + hh) * WW + ww) * VV +
                              v0 + q * 4);
      }
      *(float4*)(&s[px * SPX + q * 4]) = v4;
    }
    __syncthreads();

    float4 a0 = make_float4(0.f, 0.f, 0.f, 0.f);
    float4 a1 = make_float4(0.f, 0.f, 0.f, 0.f);
#pragma unroll
    for (int i = 0; i < KS; ++i) {
#pragma unroll
      for (int j = 0; j < KS; ++j) {
        const float* sp = &s[((ty + i) * WT + tx + j) * SPX + g * 8];
        float a = lg[i * 5 + j];
        float4 v0r = *(const float4*)(sp);
        float4 v1r = *(const float4*)(sp + 4);
        a0.x += a * v0r.x; a0.y += a * v0r.y;
        a0.z += a * v0r.z; a0.w += a * v0r.w;
        a1.x += a * v1r.x; a1.y += a * v1r.y;
        a1.z += a * v1r.z; a1.w += a * v1r.w;
      }
    }
    *(float4*)(obase + v0 + g * 8) = a0;
    *(float4*)(obase + v0 + g * 8 + 4) = a1;
  }
}

extern "C" void kernel_launch(void* const* d_in, const int* in_sizes, int n_in,
                              void* d_out, int out_size, void* d_ws,
                              size_t ws_size, hipStream_t stream) {
  const float* qry = (const float*)d_in[0]; // main [B,H,W,C]
  const float* key = (const float*)d_in[1]; // ref  [B,H,W,C]
  const float* val = (const float*)d_in[2]; // ref_value [B,H,W,V]
  float* out = (float*)d_out;               // [B,H,W,V]

  dim3 grid(BATCH * (HH / TH) * (WW / TW)); // 1152
  dim3 block(256);
  reflocal_kernel<<<grid, block, 0, stream>>>(qry, key, val, out);
}

// Round 4
// 303.716 us; speedup vs baseline: 1.0104x; 1.0104x over previous
//
#include <hip/hip_runtime.h>

// RefLocal: 5x5 windowed dot-product attention, fp32.
// B=8 H=96 W=96 C=192 V=96.
// R4 = R3 with the compile fix (plain float4 store instead of
// __builtin_nontemporal_store, which rejects HIP_vector_type).
// R3 rationale: R2's 32B/wave fragment stores caused 8x write amplification
// (WRITE_SIZE 250MB vs 28MB output + RMW fetches). Phase-2 output now staged
// in LDS and written as full-cache-line coalesced chunks.

#define BATCH 8
#define HH 96
#define WW 96
#define CH 192
#define VV 96
#define KS 5
#define PAD 2
#define TH 8
#define TW 8
#define HT (TH + 2 * PAD) // 12
#define WT (TW + 2 * PAD) // 12
#define NPIX (HT * WT)    // 144
#define CHUNK 32          // channels staged per iteration
#define SPX 36            // LDS floats per pixel (32 data + 4 pad)
#define RSTR 101          // reduction buffer stride (odd -> conflict-free)
#define SO 33             // output staging stride (odd -> 2 lanes/bank, free)

__global__ __launch_bounds__(256, 4) void reflocal_kernel(
    const float* __restrict__ qry, const float* __restrict__ key,
    const float* __restrict__ val, float* __restrict__ out) {
  // XCD swizzle: blockIdx round-robins across 8 XCDs; give each XCD one image.
  int braw = blockIdx.x;
  int L = (braw & 7) * 144 + (braw >> 3); // gridDim.x == 1152
  int bb = L / 144;
  int t2 = L - bb * 144;
  int tyy = t2 / 12;
  int txx = t2 - tyy * 12;
  int h0 = tyy * TH, w0 = txx * TW;

  int tid = threadIdx.x;
  int g = tid >> 6; // wave id 0..3 (channel-slice owner)
  int p = tid & 63; // pixel within 8x8 tile
  int ty = p >> 3, tx = p & 7;
  int h = h0 + ty, w = w0 + tx;

  // s: halo staging (144*36=5184 floats) unioned with logit-reduction
  // buffer (64*101=6464 floats). so: output staging.
  __shared__ float s[64 * RSTR]; // 25856 B
  __shared__ float so[64 * SO];  // 8448 B

  float lg[25];
#pragma unroll
  for (int o = 0; o < 25; ++o) lg[o] = 0.f;

  const float* qbase = qry + (size_t)((bb * HH + h) * WW + w) * CH;

  // ---- Phase 1: partial logits, C in chunks of 32 (wave slice = 8 ch) ----
  for (int c0 = 0; c0 < CH; c0 += CHUNK) {
    __syncthreads();
    for (int t = tid; t < NPIX * (CHUNK / 4); t += 256) {
      int px = t >> 3, q = t & 7;
      int ry = px / WT, rx = px - ry * WT;
      int hh = h0 - PAD + ry, ww = w0 - PAD + rx;
      float4 v4 = make_float4(0.f, 0.f, 0.f, 0.f);
      if ((unsigned)hh < HH && (unsigned)ww < WW) {
        v4 = *(const float4*)(key + (size_t)((bb * HH + hh) * WW + ww) * CH +
                              c0 + q * 4);
      }
      *(float4*)(&s[px * SPX + q * 4]) = v4;
    }
    __syncthreads();

    float4 m0 = *(const float4*)(qbase + c0 + g * 8);
    float4 m1 = *(const float4*)(qbase + c0 + g * 8 + 4);
#pragma unroll
    for (int i = 0; i < KS; ++i) {
#pragma unroll
      for (int j = 0; j < KS; ++j) {
        const float* sp = &s[((ty + i) * WT + tx + j) * SPX + g * 8];
        float4 k0 = *(const float4*)(sp);
        float4 k1 = *(const float4*)(sp + 4);
        lg[i * 5 + j] += m0.x * k0.x + m0.y * k0.y + m0.z * k0.z +
                         m0.w * k0.w + m1.x * k1.x + m1.y * k1.y +
                         m1.z * k1.z + m1.w * k1.w;
      }
    }
  }

  // ---- cross-wave logit reduction through LDS ----
  __syncthreads();
#pragma unroll
  for (int o = 0; o < 25; ++o) s[p * RSTR + g * 25 + o] = lg[o];
  __syncthreads();
#pragma unroll
  for (int o = 0; o < 25; ++o) {
    float v = s[p * RSTR + o];
#pragma unroll
    for (int g2 = 1; g2 < 4; ++g2) v += s[p * RSTR + g2 * 25 + o];
    lg[o] = v;
  }

  // ---- softmax over 25 (zero halo contributed logit 0 = TF SAME pad) ----
  float mx = lg[0];
#pragma unroll
  for (int o = 1; o < 25; ++o) mx = fmaxf(mx, lg[o]);
  float sum = 0.f;
#pragma unroll
  for (int o = 0; o < 25; ++o) {
    lg[o] = __expf(lg[o] - mx);
    sum += lg[o];
  }
  float inv = 1.f / sum;
#pragma unroll
  for (int o = 0; o < 25; ++o) lg[o] *= inv;

  // ---- Phase 2: values, V in chunks of 32; LDS-staged coalesced write ----
  for (int v0 = 0; v0 < VV; v0 += CHUNK) {
    __syncthreads();
    for (int t = tid; t < NPIX * (CHUNK / 4); t += 256) {
      int px = t >> 3, q = t & 7;
      int ry = px / WT, rx = px - ry * WT;
      int hh = h0 - PAD + ry, ww = w0 - PAD + rx;
      float4 v4 = make_float4(0.f, 0.f, 0.f, 0.f);
      if ((unsigned)hh < HH && (unsigned)ww < WW) {
        v4 = *(const float4*)(val + (size_t)((bb * HH + hh) * WW + ww) * VV +
                              v0 + q * 4);
      }
      *(float4*)(&s[px * SPX + q * 4]) = v4;
    }
    __syncthreads();

    float4 a0 = make_float4(0.f, 0.f, 0.f, 0.f);
    float4 a1 = make_float4(0.f, 0.f, 0.f, 0.f);
#pragma unroll
    for (int i = 0; i < KS; ++i) {
#pragma unroll
      for (int j = 0; j < KS; ++j) {
        const float* sp = &s[((ty + i) * WT + tx + j) * SPX + g * 8];
        float a = lg[i * 5 + j];
        float4 v0r = *(const float4*)(sp);
        float4 v1r = *(const float4*)(sp + 4);
        a0.x += a * v0r.x; a0.y += a * v0r.y;
        a0.z += a * v0r.z; a0.w += a * v0r.w;
        a1.x += a * v1r.x; a1.y += a * v1r.y;
        a1.z += a * v1r.z; a1.w += a * v1r.w;
      }
    }
    // stage this wave's 32B slice into LDS (stride 33: conflict-free)
    *(float4*)(&so[p * SO + g * 8]) = a0;
    *(float4*)(&so[p * SO + g * 8 + 4]) = a1;
    __syncthreads();

    // coalesced write: 8 consecutive lanes cover 128 contiguous bytes
    // (pixel stride 384B = 3*128 -> every store lands on full 64B lines)
    for (int t = tid; t < 64 * (CHUNK / 4); t += 256) {
      int px = t >> 3, c4 = (t & 7) * 4;
      int pty = px >> 3, ptx = px & 7;
      float4 v4 = *(const float4*)(&so[px * SO + c4]);
      *(float4*)(out + (size_t)((bb * HH + h0 + pty) * WW + w0 + ptx) * VV +
                 v0 + c4) = v4;
    }
  }
}

extern "C" void kernel_launch(void* const* d_in, const int* in_sizes, int n_in,
                              void* d_out, int out_size, void* d_ws,
                              size_t ws_size, hipStream_t stream) {
  const float* qry = (const float*)d_in[0]; // main [B,H,W,C]
  const float* key = (const float*)d_in[1]; // ref  [B,H,W,C]
  const float* val = (const float*)d_in[2]; // ref_value [B,H,W,V]
  float* out = (float*)d_out;               // [B,H,W,V]

  dim3 grid(BATCH * (HH / TH) * (WW / TW)); // 1152
  dim3 block(256);
  reflocal_kernel<<<grid, block, 0, stream>>>(qry, key, val, out);
}

// Round 5
// 238.195 us; speedup vs baseline: 1.2883x; 1.2751x over previous
//
#include <hip/hip_runtime.h>

// RefLocal: 5x5 windowed dot-product attention, fp32.
// B=8 H=96 W=96 C=192 V=96.
// R5 = R4 with __launch_bounds__(256, 2) instead of (256, 4).
// R4 post-mortem: VGPR_Count=64 while live state needs ~60+ temps ->
// register SPILL to scratch. Scratch WS ~4MB/CU thrashed L2 -> 230MB phantom
// EA traffic each way (WRITE_SIZE 264MB vs 28MB output), latency-bound at
// VALUBusy=11%. (256,2) raises the VGPR budget to 256/wave; actual use ~100
// gives 4-5 waves/SIMD; LDS (34.3KB) caps blocks at 4/CU = 50% occupancy.

#define BATCH 8
#define HH 96
#define WW 96
#define CH 192
#define VV 96
#define KS 5
#define PAD 2
#define TH 8
#define TW 8
#define HT (TH + 2 * PAD) // 12
#define WT (TW + 2 * PAD) // 12
#define NPIX (HT * WT)    // 144
#define CHUNK 32          // channels staged per iteration
#define SPX 36            // LDS floats per pixel (32 data + 4 pad)
#define RSTR 101          // reduction buffer stride (odd -> conflict-free)
#define SO 33             // output staging stride (odd -> 2 lanes/bank, free)

__global__ __launch_bounds__(256, 2) void reflocal_kernel(
    const float* __restrict__ qry, const float* __restrict__ key,
    const float* __restrict__ val, float* __restrict__ out) {
  // XCD swizzle: blockIdx round-robins across 8 XCDs; give each XCD one image.
  int braw = blockIdx.x;
  int L = (braw & 7) * 144 + (braw >> 3); // gridDim.x == 1152
  int bb = L / 144;
  int t2 = L - bb * 144;
  int tyy = t2 / 12;
  int txx = t2 - tyy * 12;
  int h0 = tyy * TH, w0 = txx * TW;

  int tid = threadIdx.x;
  int g = tid >> 6; // wave id 0..3 (channel-slice owner)
  int p = tid & 63; // pixel within 8x8 tile
  int ty = p >> 3, tx = p & 7;
  int h = h0 + ty, w = w0 + tx;

  // s: halo staging (144*36=5184 floats) unioned with logit-reduction
  // buffer (64*101=6464 floats). so: output staging.
  __shared__ float s[64 * RSTR]; // 25856 B
  __shared__ float so[64 * SO];  // 8448 B

  float lg[25];
#pragma unroll
  for (int o = 0; o < 25; ++o) lg[o] = 0.f;

  const float* qbase = qry + (size_t)((bb * HH + h) * WW + w) * CH;

  // ---- Phase 1: partial logits, C in chunks of 32 (wave slice = 8 ch) ----
  for (int c0 = 0; c0 < CH; c0 += CHUNK) {
    __syncthreads();
    for (int t = tid; t < NPIX * (CHUNK / 4); t += 256) {
      int px = t >> 3, q = t & 7;
      int ry = px / WT, rx = px - ry * WT;
      int hh = h0 - PAD + ry, ww = w0 - PAD + rx;
      float4 v4 = make_float4(0.f, 0.f, 0.f, 0.f);
      if ((unsigned)hh < HH && (unsigned)ww < WW) {
        v4 = *(const float4*)(key + (size_t)((bb * HH + hh) * WW + ww) * CH +
                              c0 + q * 4);
      }
      *(float4*)(&s[px * SPX + q * 4]) = v4;
    }
    __syncthreads();

    float4 m0 = *(const float4*)(qbase + c0 + g * 8);
    float4 m1 = *(const float4*)(qbase + c0 + g * 8 + 4);
#pragma unroll
    for (int i = 0; i < KS; ++i) {
#pragma unroll
      for (int j = 0; j < KS; ++j) {
        const float* sp = &s[((ty + i) * WT + tx + j) * SPX + g * 8];
        float4 k0 = *(const float4*)(sp);
        float4 k1 = *(const float4*)(sp + 4);
        lg[i * 5 + j] += m0.x * k0.x + m0.y * k0.y + m0.z * k0.z +
                         m0.w * k0.w + m1.x * k1.x + m1.y * k1.y +
                         m1.z * k1.z + m1.w * k1.w;
      }
    }
  }

  // ---- cross-wave logit reduction through LDS ----
  __syncthreads();
#pragma unroll
  for (int o = 0; o < 25; ++o) s[p * RSTR + g * 25 + o] = lg[o];
  __syncthreads();
#pragma unroll
  for (int o = 0; o < 25; ++o) {
    float v = s[p * RSTR + o];
#pragma unroll
    for (int g2 = 1; g2 < 4; ++g2) v += s[p * RSTR + g2 * 25 + o];
    lg[o] = v;
  }

  // ---- softmax over 25 (zero halo contributed logit 0 = TF SAME pad) ----
  float mx = lg[0];
#pragma unroll
  for (int o = 1; o < 25; ++o) mx = fmaxf(mx, lg[o]);
  float sum = 0.f;
#pragma unroll
  for (int o = 0; o < 25; ++o) {
    lg[o] = __expf(lg[o] - mx);
    sum += lg[o];
  }
  float inv = 1.f / sum;
#pragma unroll
  for (int o = 0; o < 25; ++o) lg[o] *= inv;

  // ---- Phase 2: values, V in chunks of 32; LDS-staged coalesced write ----
  for (int v0 = 0; v0 < VV; v0 += CHUNK) {
    __syncthreads();
    for (int t = tid; t < NPIX * (CHUNK / 4); t += 256) {
      int px = t >> 3, q = t & 7;
      int ry = px / WT, rx = px - ry * WT;
      int hh = h0 - PAD + ry, ww = w0 - PAD + rx;
      float4 v4 = make_float4(0.f, 0.f, 0.f, 0.f);
      if ((unsigned)hh < HH && (unsigned)ww < WW) {
        v4 = *(const float4*)(val + (size_t)((bb * HH + hh) * WW + ww) * VV +
                              v0 + q * 4);
      }
      *(float4*)(&s[px * SPX + q * 4]) = v4;
    }
    __syncthreads();

    float4 a0 = make_float4(0.f, 0.f, 0.f, 0.f);
    float4 a1 = make_float4(0.f, 0.f, 0.f, 0.f);
#pragma unroll
    for (int i = 0; i < KS; ++i) {
#pragma unroll
      for (int j = 0; j < KS; ++j) {
        const float* sp = &s[((ty + i) * WT + tx + j) * SPX + g * 8];
        float a = lg[i * 5 + j];
        float4 v0r = *(const float4*)(sp);
        float4 v1r = *(const float4*)(sp + 4);
        a0.x += a * v0r.x; a0.y += a * v0r.y;
        a0.z += a * v0r.z; a0.w += a * v0r.w;
        a1.x += a * v1r.x; a1.y += a * v1r.y;
        a1.z += a * v1r.z; a1.w += a * v1r.w;
      }
    }
    // stage this wave's 32B slice into LDS (stride 33: conflict-free)
    *(float4*)(&so[p * SO + g * 8]) = a0;
    *(float4*)(&so[p * SO + g * 8 + 4]) = a1;
    __syncthreads();

    // coalesced write: 8 consecutive lanes cover 128 contiguous bytes
    // (pixel stride 384B = 3*128 -> every store lands on full 64B lines)
    for (int t = tid; t < 64 * (CHUNK / 4); t += 256) {
      int px = t >> 3, c4 = (t & 7) * 4;
      int pty = px >> 3, ptx = px & 7;
      float4 v4 = *(const float4*)(&so[px * SO + c4]);
      *(float4*)(out + (size_t)((bb * HH + h0 + pty) * WW + w0 + ptx) * VV +
                 v0 + c4) = v4;
    }
  }
}

extern "C" void kernel_launch(void* const* d_in, const int* in_sizes, int n_in,
                              void* d_out, int out_size, void* d_ws,
                              size_t ws_size, hipStream_t stream) {
  const float* qry = (const float*)d_in[0]; // main [B,H,W,C]
  const float* key = (const float*)d_in[1]; // ref  [B,H,W,C]
  const float* val = (const float*)d_in[2]; // ref_value [B,H,W,V]
  float* out = (float*)d_out;               // [B,H,W,V]

  dim3 grid(BATCH * (HH / TH) * (WW / TW)); // 1152
  dim3 block(256);
  reflocal_kernel<<<grid, block, 0, stream>>>(qry, key, val, out);
}

// Round 6
// 189.770 us; speedup vs baseline: 1.6171x; 1.2552x over previous
//
#include <hip/hip_runtime.h>

// RefLocal: 5x5 windowed dot-product attention, fp32.
// B=8 H=96 W=96 C=192 V=96.
// R6 = R5 + software-pipelined staging:
//  - chunk c+1's global data prefetched into VGPRs during chunk c's window
//    FMAs (R5 exposed ~900cyc HBM latency inside the double-barrier per
//    chunk: VALUBusy 17%, LDS pipe <50% busy vs 40us ds_read floor).
//  - staging indices (pixel id, LDS dst) precomputed once, hoisted out of
//    the chunk loops.
//  - output staging reuses s[] at offset 5184 (disjoint from halo region);
//    LDS 34.3KB -> 29.2KB.

#define BATCH 8
#define HH 96
#define WW 96
#define CH 192
#define VV 96
#define KS 5
#define PAD 2
#define TH 8
#define TW 8
#define HT (TH + 2 * PAD) // 12
#define WT (TW + 2 * PAD) // 12
#define NPIX (HT * WT)    // 144
#define CHUNK 32          // channels staged per iteration
#define SPX 36            // LDS floats per pixel (32 data + 4 pad)
#define RSTR 101          // reduction stride (odd -> conflict-free)
#define SO 33             // out-stage stride (odd -> conflict-free)
#define SOFF (NPIX * SPX) // 5184: out-stage base (disjoint from halo)
#define SSZ (SOFF + 64 * SO) // 7296 floats = 29184 B (reduction needs 6464)

__global__ __launch_bounds__(256, 2) void reflocal_kernel(
    const float* __restrict__ qry, const float* __restrict__ key,
    const float* __restrict__ val, float* __restrict__ out) {
  // XCD swizzle: blockIdx round-robins across 8 XCDs; one image per XCD.
  int braw = blockIdx.x;
  int L = (braw & 7) * 144 + (braw >> 3); // gridDim.x == 1152
  int bb = L / 144;
  int t2 = L - bb * 144;
  int tyy = t2 / 12;
  int txx = t2 - tyy * 12;
  int h0 = tyy * TH, w0 = txx * TW;

  int tid = threadIdx.x;
  int g = tid >> 6; // wave id 0..3 (channel-slice owner)
  int p = tid & 63; // pixel within 8x8 tile
  int ty = p >> 3, tx = p & 7;
  int h = h0 + ty, w = w0 + tx;

  __shared__ float s[SSZ];

  // ---- precomputed staging bookkeeping (hoisted out of chunk loops) ----
  // thread handles quads t = tid + 256*r, r=0..4; t = px*8 + q, q == tid&7.
  int q4 = (tid & 7) * 4;
  int pidx[5]; // global pixel linear index, -1 = OOB (store zeros), -2 = skip
  int ldst[5]; // LDS float offset
#pragma unroll
  for (int r = 0; r < 5; ++r) {
    int px = (tid >> 3) + 32 * r;
    if (px < NPIX) {
      int ry = px / WT, rx = px - ry * WT;
      int hh = h0 - PAD + ry, ww = w0 - PAD + rx;
      pidx[r] = ((unsigned)hh < HH && (unsigned)ww < WW)
                    ? (bb * HH + hh) * WW + ww
                    : -1;
      ldst[r] = px * SPX + q4;
    } else {
      pidx[r] = -2;
      ldst[r] = 0;
    }
  }

  float lg[25];
#pragma unroll
  for (int o = 0; o < 25; ++o) lg[o] = 0.f;

  const float* qbase = qry + (size_t)((bb * HH + h) * WW + w) * CH;

  // ---- Phase 1: partial logits, C in chunks of 32 (wave slice = 8 ch) ----
  float4 pf[5];
#pragma unroll
  for (int r = 0; r < 5; ++r) { // prefetch chunk 0
    float4 v4 = make_float4(0.f, 0.f, 0.f, 0.f);
    if (pidx[r] >= 0)
      v4 = *(const float4*)(key + (size_t)pidx[r] * CH + q4);
    pf[r] = v4;
  }

  for (int c0 = 0; c0 < CH; c0 += CHUNK) {
    __syncthreads();
#pragma unroll
    for (int r = 0; r < 5; ++r)
      if (pidx[r] != -2) *(float4*)(&s[ldst[r]]) = pf[r];
    __syncthreads();
    if (c0 + CHUNK < CH) { // prefetch next chunk; waitcnt lands next iter
      int cn = c0 + CHUNK + q4;
#pragma unroll
      for (int r = 0; r < 5; ++r) {
        float4 v4 = make_float4(0.f, 0.f, 0.f, 0.f);
        if (pidx[r] >= 0)
          v4 = *(const float4*)(key + (size_t)pidx[r] * CH + cn);
        pf[r] = v4;
      }
    }

    float4 m0 = *(const float4*)(qbase + c0 + g * 8);
    float4 m1 = *(const float4*)(qbase + c0 + g * 8 + 4);
#pragma unroll
    for (int i = 0; i < KS; ++i) {
#pragma unroll
      for (int j = 0; j < KS; ++j) {
        const float* sp = &s[((ty + i) * WT + tx + j) * SPX + g * 8];
        float4 k0 = *(const float4*)(sp);
        float4 k1 = *(const float4*)(sp + 4);
        lg[i * 5 + j] += m0.x * k0.x + m0.y * k0.y + m0.z * k0.z +
                         m0.w * k0.w + m1.x * k1.x + m1.y * k1.y +
                         m1.z * k1.z + m1.w * k1.w;
      }
    }
  }

  // ---- cross-wave logit reduction through LDS ----
  __syncthreads();
#pragma unroll
  for (int o = 0; o < 25; ++o) s[p * RSTR + g * 25 + o] = lg[o];
  __syncthreads();
#pragma unroll
  for (int o = 0; o < 25; ++o) {
    float v = s[p * RSTR + o];
#pragma unroll
    for (int g2 = 1; g2 < 4; ++g2) v += s[p * RSTR + g2 * 25 + o];
    lg[o] = v;
  }

  // prefetch V chunk 0 (overlaps softmax math below)
#pragma unroll
  for (int r = 0; r < 5; ++r) {
    float4 v4 = make_float4(0.f, 0.f, 0.f, 0.f);
    if (pidx[r] >= 0)
      v4 = *(const float4*)(val + (size_t)pidx[r] * VV + q4);
    pf[r] = v4;
  }

  // ---- softmax over 25 (zero halo contributed logit 0 = TF SAME pad) ----
  float mx = lg[0];
#pragma unroll
  for (int o = 1; o < 25; ++o) mx = fmaxf(mx, lg[o]);
  float sum = 0.f;
#pragma unroll
  for (int o = 0; o < 25; ++o) {
    lg[o] = __expf(lg[o] - mx);
    sum += lg[o];
  }
  float inv = 1.f / sum;
#pragma unroll
  for (int o = 0; o < 25; ++o) lg[o] *= inv;

  // ---- Phase 2: values, V in chunks of 32; LDS-staged coalesced write ----
  for (int v0 = 0; v0 < VV; v0 += CHUNK) {
    __syncthreads(); // also covers: reduction reads done before halo overwrite
#pragma unroll
    for (int r = 0; r < 5; ++r)
      if (pidx[r] != -2) *(float4*)(&s[ldst[r]]) = pf[r];
    __syncthreads();
    if (v0 + CHUNK < VV) {
      int vn = v0 + CHUNK + q4;
#pragma unroll
      for (int r = 0; r < 5; ++r) {
        float4 v4 = make_float4(0.f, 0.f, 0.f, 0.f);
        if (pidx[r] >= 0)
          v4 = *(const float4*)(val + (size_t)pidx[r] * VV + vn);
        pf[r] = v4;
      }
    }

    float4 a0 = make_float4(0.f, 0.f, 0.f, 0.f);
    float4 a1 = make_float4(0.f, 0.f, 0.f, 0.f);
#pragma unroll
    for (int i = 0; i < KS; ++i) {
#pragma unroll
      for (int j = 0; j < KS; ++j) {
        const float* sp = &s[((ty + i) * WT + tx + j) * SPX + g * 8];
        float a = lg[i * 5 + j];
        float4 v0r = *(const float4*)(sp);
        float4 v1r = *(const float4*)(sp + 4);
        a0.x += a * v0r.x; a0.y += a * v0r.y;
        a0.z += a * v0r.z; a0.w += a * v0r.w;
        a1.x += a * v1r.x; a1.y += a * v1r.y;
        a1.z += a * v1r.z; a1.w += a * v1r.w;
      }
    }
    // stage into out-region (disjoint from halo; no barrier needed before)
    *(float4*)(&s[SOFF + p * SO + g * 8]) = a0;
    *(float4*)(&s[SOFF + p * SO + g * 8 + 4]) = a1;
    __syncthreads();

    // coalesced write: 8 consecutive lanes cover 128 contiguous bytes
    for (int t = tid; t < 64 * (CHUNK / 4); t += 256) {
      int px = t >> 3, c4 = (t & 7) * 4;
      int pty = px >> 3, ptx = px & 7;
      float4 v4 = *(const float4*)(&s[SOFF + px * SO + c4]);
      *(float4*)(out + (size_t)((bb * HH + h0 + pty) * WW + w0 + ptx) * VV +
                 v0 + c4) = v4;
    }
  }
}

extern "C" void kernel_launch(void* const* d_in, const int* in_sizes, int n_in,
                              void* d_out, int out_size, void* d_ws,
                              size_t ws_size, hipStream_t stream) {
  const float* qry = (const float*)d_in[0]; // main [B,H,W,C]
  const float* key = (const float*)d_in[1]; // ref  [B,H,W,C]
  const float* val = (const float*)d_in[2]; // ref_value [B,H,W,V]
  float* out = (float*)d_out;               // [B,H,W,V]

  dim3 grid(BATCH * (HH / TH) * (WW / TW)); // 1152
  dim3 block(256);
  reflocal_kernel<<<grid, block, 0, stream>>>(qry, key, val, out);
}